// Round 9
// baseline (125.702 us; speedup 1.0000x reference)
//
#include <hip/hip_runtime.h>
#include <math.h>

typedef float f4 __attribute__((ext_vector_type(4)));

#define BDIM 256

__device__ __forceinline__ float dot4(f4 a, f4 w) {
    return a[0]*w[0] + a[1]*w[1] + a[2]*w[2] + a[3]*w[3];
}

__device__ __forceinline__ f4 rot4(f4 v, int src) {
    f4 r;
    r[0] = __shfl(v[0], src, 64);
    r[1] = __shfl(v[1], src, 64);
    r[2] = __shfl(v[2], src, 64);
    r[3] = __shfl(v[3], src, 64);
    return r;
}

// Wave-autonomous kernel: one wave = one row-pair (rows 2k, 2k+1).
// Per-tensor chunk C = flat f4 [150k, 150k+150): v0=C[lane], v1=C[64+lane],
// v2=C[128+lane] (lanes<22). Row0 = idx 0..74, row1 = idx 75..149.
// No barriers, no shared memory arrays.
__global__ __launch_bounds__(BDIM, 4) void taskselector_kernel(
    const f4* __restrict__ se1,
    const f4* __restrict__ se2,
    const float* __restrict__ W,
    const float* __restrict__ bvec,
    const f4* __restrict__ u4,
    f4* __restrict__ out)
{
    const int tid  = threadIdx.x;
    const int lane = tid & 63;
    const int wave = tid >> 6;
    const int k    = blockIdx.x * 4 + wave;       // row-pair index

    const f4 zero = (f4)0.f;
    const bool lt11 = (lane < 11);
    const bool lt22 = (lane < 22);

    // ---- data loads (issue first; W-fragment gathers overlap the latency) ----
    const f4* C1 = se1 + (size_t)k * 150;
    const f4* C2 = se2 + (size_t)k * 150;
    f4 v0 = __builtin_nontemporal_load(C1 + lane);
    f4 v1 = __builtin_nontemporal_load(C1 + 64 + lane);
    f4 v2 = lt22 ? __builtin_nontemporal_load(C1 + 128 + lane) : zero;
    f4 v3 = __builtin_nontemporal_load(C2 + lane);
    f4 v4 = __builtin_nontemporal_load(C2 + 64 + lane);
    f4 v5 = lt22 ? __builtin_nontemporal_load(C2 + 128 + lane) : zero;
    f4 uu = u4[k];   // u floats [4k..4k+4): row0 -> uu[0],uu[1]; row1 -> uu[2],uu[3]

    // ---- per-lane W fragments (L1-resident, 4.8 KB total) ----
    // v0 holds row0 pos lane          -> W f4 [lane]        (se1) / [75+lane]  (se2: v3)
    // v1: lane<11 row0 pos 64+lane    -> W [64+lane]        / [139+lane] (v4)
    //     lane>=11 row1 pos lane-11   -> W [lane-11]        / [64+lane]  (v4)
    // v2 (lane<22) row1 pos 53+lane   -> W [53+lane]        / [128+lane] (v5)
    const f4* Wf0 = (const f4*)W;          // task0: 150 f4
    const f4* Wf1 = (const f4*)(W + 600);  // task1
    const int iB1 = lt11 ? 64 + lane : lane - 11;
    const int iB2 = lt11 ? 139 + lane : 64 + lane;
    f4 wA1_0 = Wf0[lane],      wA1_1 = Wf1[lane];
    f4 wA2_0 = Wf0[75 + lane], wA2_1 = Wf1[75 + lane];
    f4 wB1_0 = Wf0[iB1],       wB1_1 = Wf1[iB1];
    f4 wB2_0 = Wf0[iB2],       wB2_1 = Wf1[iB2];
    f4 wC1_0 = lt22 ? Wf0[53 + lane]  : zero;
    f4 wC1_1 = lt22 ? Wf1[53 + lane]  : zero;
    f4 wC2_0 = lt22 ? Wf0[128 + lane] : zero;
    f4 wC2_1 = lt22 ? Wf1[128 + lane] : zero;
    const float b0 = bvec[0];
    const float b1 = bvec[1];

    // ---- per-lane partials; v1/v4 attributed to row0 (lane<11) or row1 ----
    float dB0 = dot4(v1, wB1_0) + dot4(v4, wB2_0);
    float dB1 = dot4(v1, wB1_1) + dot4(v4, wB2_1);
    float p00 = dot4(v0, wA1_0) + dot4(v3, wA2_0) + (lt11 ? dB0 : 0.f);
    float p01 = dot4(v0, wA1_1) + dot4(v3, wA2_1) + (lt11 ? dB1 : 0.f);
    float p10 = (lt11 ? 0.f : dB0) + dot4(v2, wC1_0) + dot4(v5, wC2_0);
    float p11 = (lt11 ? 0.f : dB1) + dot4(v2, wC1_1) + dot4(v5, wC2_1);

    // ---- 64-lane butterfly, 4 interleaved chains ----
    #pragma unroll
    for (int off = 32; off > 0; off >>= 1) {
        p00 += __shfl_xor(p00, off, 64);
        p01 += __shfl_xor(p01, off, 64);
        p10 += __shfl_xor(p10, off, 64);
        p11 += __shfl_xor(p11, off, 64);
    }

    // ---- epilogues (identical formula to the proven absmax-0 version) ----
    float sel00, sel01, sel10, sel11;
    {   // row0
        float z0 = fmaxf(p00 + b0, 0.f);
        float z1 = fmaxf(p01 + b1, 0.f);
        float m  = fmaxf(z0, z1);
        float lse = m + logf(expf(z0 - m) + expf(z1 - m));
        float q0 = (z0 - lse) + (-logf(-logf(uu[0] + 1e-20f) + 1e-20f));
        float q1 = (z1 - lse) + (-logf(-logf(uu[1] + 1e-20f) + 1e-20f));
        float mm = fmaxf(q0, q1);
        float e0 = expf(q0 - mm);
        float e1 = expf(q1 - mm);
        float s  = e0 + e1;
        float y0 = e0 / s;
        float y1 = e1 / s;
        bool  pick0 = (q0 >= q1);
        sel00 = pick0 ? ((1.f - y0) + y0) : 0.f;
        sel01 = pick0 ? 0.f : ((1.f - y1) + y1);
    }
    {   // row1
        float z0 = fmaxf(p10 + b0, 0.f);
        float z1 = fmaxf(p11 + b1, 0.f);
        float m  = fmaxf(z0, z1);
        float lse = m + logf(expf(z0 - m) + expf(z1 - m));
        float q0 = (z0 - lse) + (-logf(-logf(uu[2] + 1e-20f) + 1e-20f));
        float q1 = (z1 - lse) + (-logf(-logf(uu[3] + 1e-20f) + 1e-20f));
        float mm = fmaxf(q0, q1);
        float e0 = expf(q0 - mm);
        float e1 = expf(q1 - mm);
        float s  = e0 + e1;
        float y0 = e0 / s;
        float y1 = e1 / s;
        bool  pick0 = (q0 >= q1);
        sel10 = pick0 ? ((1.f - y0) + y0) : 0.f;
        sel11 = pick0 ? 0.f : ((1.f - y1) + y1);
    }

    // ---- redistribute for stores: 6 constant rotates (rot-11 / rot-22) ----
    const int r11 = (lane + 53) & 63;   // src: lane>=11 -> lane-11 ; lane<11 -> lane+53
    const int r22 = (lane + 42) & 63;   // src: lane>=22 -> lane-22 ; lane<22 -> lane+42
    f4 v1r = rot4(v1, r11);
    f4 v2r = rot4(v2, r11);
    f4 v3r = rot4(v3, r11);
    f4 v4r = rot4(v4, r11);
    f4 v4s = rot4(v4, r22);
    f4 v5s = rot4(v5, r22);

    // ---- stores: out chunk O = flat f4 [300k, 300k+300)
    // layout: [0,75) row0·se1 | [75,150) row0·se2 | [150,225) row1·se1 | [225,300) row1·se2
    f4* O = out + (size_t)k * 300;
    // s0: j=lane (<64<75): C1[lane]=v0
    __builtin_nontemporal_store(v0 * sel00, O + lane);
    // s1: j=64+lane. lane<11: C1[64+lane]=v1 | lane>=11: C2[lane-11]=v3r
    __builtin_nontemporal_store(lt11 ? v1 * sel00 : v3r * sel01, O + 64 + lane);
    // s2: j=128+lane. lane<11: C2[53+lane]=v3r | 11<=lane<22: C2[64+(lane-11)]=v4r
    //                | lane>=22: C1[64+(lane-11)]=v1r (row1)
    __builtin_nontemporal_store(
        lt11 ? v3r * sel01 : (lt22 ? v4r * sel01 : v1r * sel10), O + 128 + lane);
    // s3: j=192+lane. lane<11: C1[64+53+lane]=v1r | 11<=lane<33: C1[128+(lane-11)]=v2r
    //                | lane>=33: C2[64+(lane-22)]=v4s (row1 se2)
    __builtin_nontemporal_store(
        lt11 ? v1r * sel10 : ((lane < 33) ? v2r * sel10 : v4s * sel11), O + 192 + lane);
    // s4 (lane<44): j=256+lane. lane<22: C2[64+42+lane]=v4s | 22<=lane<44: C2[128+(lane-22)]=v5s
    if (lane < 44)
        __builtin_nontemporal_store(lt22 ? v4s * sel11 : v5s * sel11, O + 256 + lane);
}

extern "C" void kernel_launch(void* const* d_in, const int* in_sizes, int n_in,
                              void* d_out, int out_size, void* d_ws, size_t ws_size,
                              hipStream_t stream) {
    const f4* se1 = (const f4*)d_in[0];
    const f4* se2 = (const f4*)d_in[1];
    const float* W = (const float*)d_in[2];
    const float* b = (const float*)d_in[3];
    const f4* u4  = (const f4*)d_in[4];
    f4* out = (f4*)d_out;

    const int Brows  = in_sizes[0] / 300;    // 131072
    const int pairs  = Brows / 2;            // 65536
    const int blocks = pairs / 4;            // 16384 (exact; 4 waves/block)

    taskselector_kernel<<<blocks, BDIM, 0, stream>>>(se1, se2, W, b, u4, out);
}